// Round 1
// baseline (845.330 us; speedup 1.0000x reference)
//
#include <hip/hip_runtime.h>
#include <math.h>

#define NB 512
#define LONGN 1000
#define SHORTN 50
#define TOPKN 50

__device__ __forceinline__ float dot4(float4 a, float4 b) {
  return a.x*b.x + a.y*b.y + a.z*b.z + a.w*b.w;
}

template<int N>
__device__ __forceinline__ float dotN(const float* w, const float* x) {
  const float4* w4 = (const float4*)w;
  const float4* x4 = (const float4*)x;
  float a0 = 0.f, a1 = 0.f, a2 = 0.f, a3 = 0.f;
  #pragma unroll
  for (int k = 0; k < N/4; k += 4) {
    a0 += dot4(w4[k],   x4[k]);
    a1 += dot4(w4[k+1], x4[k+1]);
    a2 += dot4(w4[k+2], x4[k+2]);
    a3 += dot4(w4[k+3], x4[k+3]);
  }
  return (a0 + a1) + (a2 + a3);
}

__device__ __forceinline__ float wave_sum(float v) {
  #pragma unroll
  for (int off = 32; off > 0; off >>= 1) v += __shfl_xor(v, off);
  return v;
}
__device__ __forceinline__ float wave_max(float v) {
  #pragma unroll
  for (int off = 32; off > 0; off >>= 1) v = fmaxf(v, __shfl_xor(v, off));
  return v;
}

// ---------------------------------------------------------------------------
// Kernel 1: target proj + hard search (scores, softmax, top-50, hard_repr)
//           + long-history mean + SDIM hash soft search. One block per row.
// ---------------------------------------------------------------------------
__global__ __launch_bounds__(256) void hardsoft_kernel(
    const int* __restrict__ target_item_id,
    const int* __restrict__ long_hist_ids,
    const float* __restrict__ item_emb,
    const float* __restrict__ tproj_w, const float* __restrict__ tproj_b,
    const float* __restrict__ attn_w1, const float* __restrict__ attn_b1,
    const float* __restrict__ attn_w2, const float* __restrict__ attn_b2,
    const float* __restrict__ hash_emb,
    const float* __restrict__ sdim_w, const float* __restrict__ sdim_b,
    float* __restrict__ hard_out, float* __restrict__ soft_out)
{
  __shared__ __align__(16) float A4[64*64];     // A_b[i][j] = w1[i,64+j] + w1[i,128+j]*te[j]
  __shared__ __align__(16) float tv[64];        // raw target item emb
  __shared__ __align__(16) float te[64];        // projected target emb
  __shared__ __align__(16) float2 cw[64];       // (.x = c_b[i], .y = w2[i])
  __shared__ __align__(16) float scores[LONGN];
  __shared__ int   idsL[LONGN];
  __shared__ __align__(16) float redE[4*64];
  __shared__ __align__(16) float vecbuf[64];
  __shared__ float redV[4];
  __shared__ int   redI[4];
  __shared__ float selV[TOPKN];
  __shared__ int   selI[TOPKN];

  const int b = blockIdx.x;
  const int tid = threadIdx.x;
  const int wid = tid >> 6, lane = tid & 63;

  // ---- phase 0: load ids, target emb, build per-row A, c, w2 ----
  if (tid < 64) tv[tid] = item_emb[target_item_id[b]*64 + tid];
  for (int l = tid; l < LONGN; l += 256) idsL[l] = long_hist_ids[b*LONGN + l];
  __syncthreads();
  if (tid < 64) te[tid] = tproj_b[tid] + dotN<64>(tproj_w + tid*64, tv);
  __syncthreads();
  if (tid < 64) {
    float c = attn_b1[tid] + dotN<64>(attn_w1 + tid*192, te);
    cw[tid] = make_float2(c, attn_w2[tid]);
  }
  for (int idx = tid; idx < 4096; idx += 256) {
    int i = idx >> 6, j = idx & 63;
    A4[idx] = attn_w1[i*192 + 64 + j] + attn_w1[i*192 + 128 + j]*te[j];
  }
  __syncthreads();

  // ---- phase 1: scores for 1000 items (2 items per lane per round) ----
  const float b2s = attn_b2[0];
  for (int base = 0; base < LONGN; base += 512) {
    const int l0 = base + tid;
    const int l1 = l0 + 256;
    const bool has1 = (l1 < LONGN);
    const int id0 = idsL[l0];
    const int id1 = idsL[has1 ? l1 : l0];
    const float4* ep0 = (const float4*)(item_emb + id0*64);
    const float4* ep1 = (const float4*)(item_emb + id1*64);
    float4 e0[16], e1[16];
    #pragma unroll
    for (int k = 0; k < 16; ++k) { e0[k] = ep0[k]; e1[k] = ep1[k]; }
    float sc0 = b2s, sc1 = b2s;
    for (int i = 0; i < 64; ++i) {
      const float4* Ar = (const float4*)(A4 + i*64);
      float h00=0.f,h01=0.f,h02=0.f,h03=0.f;
      float h10=0.f,h11=0.f,h12=0.f,h13=0.f;
      #pragma unroll
      for (int k = 0; k < 16; k += 4) {
        float4 a0 = Ar[k], a1 = Ar[k+1], a2 = Ar[k+2], a3 = Ar[k+3];
        h00 += dot4(a0, e0[k]);   h01 += dot4(a1, e0[k+1]);
        h02 += dot4(a2, e0[k+2]); h03 += dot4(a3, e0[k+3]);
        h10 += dot4(a0, e1[k]);   h11 += dot4(a1, e1[k+1]);
        h12 += dot4(a2, e1[k+2]); h13 += dot4(a3, e1[k+3]);
      }
      float2 c2 = cw[i];
      float hh0 = ((h00+h01)+(h02+h03)) + c2.x;
      float hh1 = ((h10+h11)+(h12+h13)) + c2.x;
      sc0 += c2.y * fmaxf(hh0, 0.f);
      sc1 += c2.y * fmaxf(hh1, 0.f);
    }
    scores[l0] = sc0;
    if (has1) scores[l1] = sc1;
  }

  // ---- phase 1b: sum of long embeddings (for SDIM mean) ----
  float accE = 0.f;
  for (int l = wid; l < LONGN; l += 4)
    accE += item_emb[idsL[l]*64 + lane];
  redE[wid*64 + lane] = accE;
  __syncthreads();
  if (wid == 0)
    vecbuf[lane] = (redE[lane] + redE[64+lane] + redE[128+lane] + redE[192+lane]) * (1.f/1000.f);
  __syncthreads();

  // ---- phase 1c: hash bucket accumulation ----
  {
    const int hl = lane >> 4, dd = lane & 15;
    const float* hb = hash_emb + hl*1024*16 + dd;
    float accH = 0.f;
    for (int l = wid; l < LONGN; l += 4)
      accH += hb[(idsL[l] & 1023)*16];
    redE[wid*64 + lane] = accH;
  }
  __syncthreads();
  if (wid == 0)
    vecbuf[lane] += (redE[lane] + redE[64+lane] + redE[128+lane] + redE[192+lane]) * (1.f/1000.f);
  __syncthreads();
  // soft_repr = sdim_w @ (hash_repr + meanE) + sdim_b
  if (tid < 64)
    soft_out[b*64 + tid] = sdim_b[tid] + dotN<64>(sdim_w + tid*64, vecbuf);

  // ---- phase 2: softmax over 1000 scores -> attn probabilities ----
  float mx = -INFINITY;
  for (int l = tid; l < LONGN; l += 256) mx = fmaxf(mx, scores[l]);
  mx = wave_max(mx);
  if (lane == 0) redV[wid] = mx;
  __syncthreads();
  mx = fmaxf(fmaxf(redV[0], redV[1]), fmaxf(redV[2], redV[3]));
  __syncthreads();
  float sm = 0.f;
  for (int l = tid; l < LONGN; l += 256) {
    float a = expf(scores[l] - mx);
    scores[l] = a;
    sm += a;
  }
  sm = wave_sum(sm);
  if (lane == 0) redV[wid] = sm;
  __syncthreads();
  {
    const float inv = 1.f / (redV[0] + redV[1] + redV[2] + redV[3]);
    for (int l = tid; l < LONGN; l += 256) scores[l] *= inv;
  }
  __syncthreads();

  // ---- phase 3: iterative top-50 (max value, ties -> smallest index) ----
  for (int r = 0; r < TOPKN; ++r) {
    float bv = -1.f; int bi = 0x7fffffff;
    for (int l = tid; l < LONGN; l += 256) {
      float v = scores[l];
      if (v > bv || (v == bv && l < bi)) { bv = v; bi = l; }
    }
    #pragma unroll
    for (int off = 32; off > 0; off >>= 1) {
      float ov = __shfl_xor(bv, off);
      int   oi = __shfl_xor(bi, off);
      if (ov > bv || (ov == bv && oi < bi)) { bv = ov; bi = oi; }
    }
    if (lane == 0) { redV[wid] = bv; redI[wid] = bi; }
    __syncthreads();
    if (tid == 0) {
      float fv = redV[0]; int fi = redI[0];
      #pragma unroll
      for (int w = 1; w < 4; ++w)
        if (redV[w] > fv || (redV[w] == fv && redI[w] < fi)) { fv = redV[w]; fi = redI[w]; }
      selV[r] = fv; selI[r] = fi;
      scores[fi] = -1.f;   // remove winner (attn values are >= 0)
    }
    __syncthreads();
  }

  // ---- phase 4: softmax over the 50 selected attn values ----
  if (wid == 0) {
    float v = (lane < TOPKN) ? selV[lane] : -INFINITY;
    float m2 = wave_max(v);
    float e = (lane < TOPKN) ? expf(v - m2) : 0.f;
    float s2 = wave_sum(e);
    if (lane < TOPKN) selV[lane] = e / s2;
  }
  __syncthreads();

  // ---- phase 5: hard_repr = sum_r w_r * emb[ids[sel_r]] ----
  float accR = 0.f;
  for (int r = wid; r < TOPKN; r += 4)
    accR += selV[r] * item_emb[idsL[selI[r]]*64 + lane];
  redE[wid*64 + lane] = accR;
  __syncthreads();
  if (wid == 0)
    hard_out[b*64 + lane] = redE[lane] + redE[64+lane] + redE[128+lane] + redE[192+lane];
}

// ---------------------------------------------------------------------------
// Kernel 2: 2-layer BST transformer over short history. One block per row.
// ---------------------------------------------------------------------------
__global__ __launch_bounds__(256) void bst_kernel(
    const int* __restrict__ short_ids, const float* __restrict__ item_emb,
    const float* __restrict__ qkv_w, const float* __restrict__ qkv_b,
    const float* __restrict__ out_w, const float* __restrict__ out_b,
    const float* __restrict__ ln1_g, const float* __restrict__ ln1_b,
    const float* __restrict__ ff1_w, const float* __restrict__ ff1_b,
    const float* __restrict__ ff2_w, const float* __restrict__ ff2_b,
    const float* __restrict__ ln2_g, const float* __restrict__ ln2_b,
    float* __restrict__ bst_out)
{
  __shared__ __align__(16) float xb[SHORTN*64];     // 12.8 KB  (current x)
  __shared__ __align__(16) float buf[SHORTN*192];   // 38.4 KB  (qkv; aliased: yb=buf[0:3200], f1=buf[3200:9600])
  __shared__ __align__(16) float ob[SHORTN*64];     // 12.8 KB  (attention output)

  float* yb = buf;           // residual-sum buffer (qkv dead by then)
  float* f1 = buf + 3200;    // ff hidden (50x128)

  const int b = blockIdx.x, tid = threadIdx.x;
  const int wid = tid >> 6, lane = tid & 63;

  for (int idx = tid; idx < SHORTN*64; idx += 256) {
    int s = idx >> 6, j = idx & 63;
    xb[idx] = item_emb[short_ids[b*SHORTN + s]*64 + j];
  }
  __syncthreads();

  for (int l = 0; l < 2; ++l) {
    const float* qw = qkv_w + l*192*64;
    const float* qb = qkv_b + l*192;
    // qkv projection: buf[s*192 + o]
    for (int idx = tid; idx < SHORTN*192; idx += 256) {
      int s = idx / 192, o = idx - s*192;
      buf[idx] = qb[o] + dotN<64>(qw + o*64, xb + s*64);
    }
    __syncthreads();
    // attention: thread (h,s), two-pass (max, then exp-weighted accumulate)
    if (tid < 4*SHORTN) {
      const int h = tid / SHORTN, s = tid - h*SHORTN;
      float4 q4[4];
      #pragma unroll
      for (int k = 0; k < 4; ++k) q4[k] = ((const float4*)(buf + s*192 + h*16))[k];
      float mxa = -INFINITY;
      for (int t2 = 0; t2 < SHORTN; ++t2) {
        const float4* kp = (const float4*)(buf + t2*192 + 64 + h*16);
        float d = dot4(q4[0],kp[0]) + dot4(q4[1],kp[1]) + dot4(q4[2],kp[2]) + dot4(q4[3],kp[3]);
        mxa = fmaxf(mxa, d*0.25f);
      }
      float ss = 0.f;
      float4 oa0 = {0,0,0,0}, oa1 = {0,0,0,0}, oa2 = {0,0,0,0}, oa3 = {0,0,0,0};
      for (int t2 = 0; t2 < SHORTN; ++t2) {
        const float4* kp = (const float4*)(buf + t2*192 + 64 + h*16);
        float d = dot4(q4[0],kp[0]) + dot4(q4[1],kp[1]) + dot4(q4[2],kp[2]) + dot4(q4[3],kp[3]);
        float a = expf(d*0.25f - mxa);
        ss += a;
        const float4* vp = (const float4*)(buf + t2*192 + 128 + h*16);
        float4 v0 = vp[0], v1 = vp[1], v2 = vp[2], v3 = vp[3];
        oa0.x += a*v0.x; oa0.y += a*v0.y; oa0.z += a*v0.z; oa0.w += a*v0.w;
        oa1.x += a*v1.x; oa1.y += a*v1.y; oa1.z += a*v1.z; oa1.w += a*v1.w;
        oa2.x += a*v2.x; oa2.y += a*v2.y; oa2.z += a*v2.z; oa2.w += a*v2.w;
        oa3.x += a*v3.x; oa3.y += a*v3.y; oa3.z += a*v3.z; oa3.w += a*v3.w;
      }
      const float inv = 1.f/ss;
      float4* op = (float4*)(ob + s*64 + h*16);
      oa0.x*=inv; oa0.y*=inv; oa0.z*=inv; oa0.w*=inv; op[0]=oa0;
      oa1.x*=inv; oa1.y*=inv; oa1.z*=inv; oa1.w*=inv; op[1]=oa1;
      oa2.x*=inv; oa2.y*=inv; oa2.z*=inv; oa2.w*=inv; op[2]=oa2;
      oa3.x*=inv; oa3.y*=inv; oa3.z*=inv; oa3.w*=inv; op[3]=oa3;
    }
    __syncthreads();
    // out projection + residual -> yb (qkv in buf is dead now; yb aliases it)
    for (int idx = tid; idx < SHORTN*64; idx += 256) {
      int s = idx >> 6, i = idx & 63;
      yb[idx] = xb[idx] + out_b[l*64+i] + dotN<64>(out_w + l*4096 + i*64, ob + s*64);
    }
    __syncthreads();
    // LN1 -> xb
    {
      const float g = ln1_g[l*64 + lane], bb = ln1_b[l*64 + lane];
      for (int s = wid; s < SHORTN; s += 4) {
        float v = yb[s*64 + lane];
        float mean = wave_sum(v) * (1.f/64.f);
        float dv = v - mean;
        float var = wave_sum(dv*dv) * (1.f/64.f);
        xb[s*64 + lane] = dv / sqrtf(var + 1e-5f) * g + bb;
      }
    }
    __syncthreads();
    // ff1: relu -> f1 (upper half of buf)
    for (int idx = tid; idx < SHORTN*128; idx += 256) {
      int s = idx >> 7, u = idx & 127;
      f1[idx] = fmaxf(ff1_b[l*128+u] + dotN<64>(ff1_w + l*8192 + u*64, xb + s*64), 0.f);
    }
    __syncthreads();
    // ff2 + residual -> yb (lower half of buf; no overlap with f1)
    for (int idx = tid; idx < SHORTN*64; idx += 256) {
      int s = idx >> 6, i = idx & 63;
      yb[idx] = xb[idx] + ff2_b[l*64+i] + dotN<128>(ff2_w + l*8192 + i*128, f1 + s*128);
    }
    __syncthreads();
    // LN2 -> xb
    {
      const float g = ln2_g[l*64 + lane], bb = ln2_b[l*64 + lane];
      for (int s = wid; s < SHORTN; s += 4) {
        float v = yb[s*64 + lane];
        float mean = wave_sum(v) * (1.f/64.f);
        float dv = v - mean;
        float var = wave_sum(dv*dv) * (1.f/64.f);
        xb[s*64 + lane] = dv / sqrtf(var + 1e-5f) * g + bb;
      }
    }
    __syncthreads();
  }
  // mean over sequence
  float acc = 0.f;
  for (int s = wid; s < SHORTN; s += 4) acc += xb[s*64 + lane];
  __syncthreads();
  yb[wid*64 + lane] = acc;
  __syncthreads();
  if (wid == 0)
    bst_out[b*64 + lane] = (yb[lane] + yb[64+lane] + yb[128+lane] + yb[192+lane]) / 50.f;
}

// ---------------------------------------------------------------------------
// Kernel 3: fusion MLP. One block per row.
// ---------------------------------------------------------------------------
__global__ __launch_bounds__(256) void fusion_kernel(
    const float* __restrict__ user, const float* __restrict__ hard,
    const float* __restrict__ soft, const float* __restrict__ bst,
    const float* __restrict__ w1, const float* __restrict__ b1,
    const float* __restrict__ w2, const float* __restrict__ b2,
    const float* __restrict__ w3, const float* __restrict__ b3,
    float* __restrict__ out)
{
  __shared__ __align__(16) float comb[256];
  __shared__ __align__(16) float h1[256];
  __shared__ __align__(16) float h2[128];
  const int b = blockIdx.x, tid = threadIdx.x;
  if (tid < 64)       comb[tid] = user[b*64 + tid];
  else if (tid < 128) comb[tid] = hard[b*64 + tid - 64];
  else if (tid < 192) comb[tid] = soft[b*64 + tid - 128];
  else                comb[tid] = bst[b*64 + tid - 192];
  __syncthreads();
  h1[tid] = fmaxf(b1[tid] + dotN<256>(w1 + tid*256, comb), 0.f);
  __syncthreads();
  if (tid < 128) h2[tid] = fmaxf(b2[tid] + dotN<256>(w2 + tid*256, h1), 0.f);
  __syncthreads();
  if (tid < 64) {
    float p = w3[tid]*h2[tid] + w3[tid+64]*h2[tid+64];
    p = wave_sum(p);
    if (tid == 0) out[b] = p + b3[0];
  }
}

extern "C" void kernel_launch(void* const* d_in, const int* in_sizes, int n_in,
                              void* d_out, int out_size, void* d_ws, size_t ws_size,
                              hipStream_t stream) {
  const float* user_features  = (const float*)d_in[0];
  const int*   target_item_id = (const int*)  d_in[1];
  const int*   short_hist_ids = (const int*)  d_in[2];
  const int*   long_hist_ids  = (const int*)  d_in[3];
  const float* item_emb       = (const float*)d_in[4];
  const float* tproj_w  = (const float*)d_in[5];
  const float* tproj_b  = (const float*)d_in[6];
  const float* attn_w1  = (const float*)d_in[7];
  const float* attn_b1  = (const float*)d_in[8];
  const float* attn_w2  = (const float*)d_in[9];
  const float* attn_b2  = (const float*)d_in[10];
  const float* hash_emb = (const float*)d_in[11];
  const float* sdim_w   = (const float*)d_in[12];
  const float* sdim_b   = (const float*)d_in[13];
  const float* tf_qkv_w = (const float*)d_in[14];
  const float* tf_qkv_b = (const float*)d_in[15];
  const float* tf_out_w = (const float*)d_in[16];
  const float* tf_out_b = (const float*)d_in[17];
  const float* tf_ln1_g = (const float*)d_in[18];
  const float* tf_ln1_b = (const float*)d_in[19];
  const float* tf_ff1_w = (const float*)d_in[20];
  const float* tf_ff1_b = (const float*)d_in[21];
  const float* tf_ff2_w = (const float*)d_in[22];
  const float* tf_ff2_b = (const float*)d_in[23];
  const float* tf_ln2_g = (const float*)d_in[24];
  const float* tf_ln2_b = (const float*)d_in[25];
  const float* fus_w1   = (const float*)d_in[26];
  const float* fus_b1   = (const float*)d_in[27];
  const float* fus_w2   = (const float*)d_in[28];
  const float* fus_b2   = (const float*)d_in[29];
  const float* fus_w3   = (const float*)d_in[30];
  const float* fus_b3   = (const float*)d_in[31];

  float* hard = (float*)d_ws;
  float* soft = hard + NB*64;
  float* bst  = soft + NB*64;

  hardsoft_kernel<<<NB, 256, 0, stream>>>(target_item_id, long_hist_ids, item_emb,
      tproj_w, tproj_b, attn_w1, attn_b1, attn_w2, attn_b2,
      hash_emb, sdim_w, sdim_b, hard, soft);
  bst_kernel<<<NB, 256, 0, stream>>>(short_hist_ids, item_emb, tf_qkv_w, tf_qkv_b,
      tf_out_w, tf_out_b, tf_ln1_g, tf_ln1_b, tf_ff1_w, tf_ff1_b, tf_ff2_w, tf_ff2_b,
      tf_ln2_g, tf_ln2_b, bst);
  fusion_kernel<<<NB, 256, 0, stream>>>(user_features, hard, soft, bst,
      fus_w1, fus_b1, fus_w2, fus_b2, fus_w3, fus_b3, (float*)d_out);
}

// Round 2
// 654.757 us; speedup vs baseline: 1.2911x; 1.2911x over previous
//
#include <hip/hip_runtime.h>
#include <math.h>

#define NB 512
#define LONGN 1000
#define SHORTN 50
#define TOPKN 50

__device__ __forceinline__ float dot4(float4 a, float4 b) {
  return a.x*b.x + a.y*b.y + a.z*b.z + a.w*b.w;
}

template<int N>
__device__ __forceinline__ float dotN(const float* w, const float* x) {
  const float4* w4 = (const float4*)w;
  const float4* x4 = (const float4*)x;
  float a0 = 0.f, a1 = 0.f, a2 = 0.f, a3 = 0.f;
  #pragma unroll
  for (int k = 0; k < N/4; k += 4) {
    a0 += dot4(w4[k],   x4[k]);
    a1 += dot4(w4[k+1], x4[k+1]);
    a2 += dot4(w4[k+2], x4[k+2]);
    a3 += dot4(w4[k+3], x4[k+3]);
  }
  return (a0 + a1) + (a2 + a3);
}

// dot of 16 float4 (weights in regs) with an LDS/float4 stream
__device__ __forceinline__ float dotw16(const float4* w, const float4* x) {
  float a0=0.f,a1=0.f,a2=0.f,a3=0.f;
  #pragma unroll
  for (int k = 0; k < 16; k += 4) {
    a0 += dot4(w[k],   x[k]);
    a1 += dot4(w[k+1], x[k+1]);
    a2 += dot4(w[k+2], x[k+2]);
    a3 += dot4(w[k+3], x[k+3]);
  }
  return (a0+a1)+(a2+a3);
}

__device__ __forceinline__ float wave_sum(float v) {
  #pragma unroll
  for (int off = 32; off > 0; off >>= 1) v += __shfl_xor(v, off);
  return v;
}
__device__ __forceinline__ float wave_max(float v) {
  #pragma unroll
  for (int off = 32; off > 0; off >>= 1) v = fmaxf(v, __shfl_xor(v, off));
  return v;
}

// ---------------------------------------------------------------------------
// Kernel 1: target proj + hard search (scores, softmax, top-50, hard_repr)
//           + long-history mean + SDIM hash soft search. One block per row.
// ---------------------------------------------------------------------------
__global__ __launch_bounds__(256) void hardsoft_kernel(
    const int* __restrict__ target_item_id,
    const int* __restrict__ long_hist_ids,
    const float* __restrict__ item_emb,
    const float* __restrict__ tproj_w, const float* __restrict__ tproj_b,
    const float* __restrict__ attn_w1, const float* __restrict__ attn_b1,
    const float* __restrict__ attn_w2, const float* __restrict__ attn_b2,
    const float* __restrict__ hash_emb,
    const float* __restrict__ sdim_w, const float* __restrict__ sdim_b,
    float* __restrict__ hard_out, float* __restrict__ soft_out)
{
  __shared__ __align__(16) float A4[64*64];     // A_b[i][j] = w1[i,64+j] + w1[i,128+j]*te[j]
  __shared__ __align__(16) float tv[64];        // raw target item emb
  __shared__ __align__(16) float te[64];        // projected target emb
  __shared__ __align__(16) float2 cw[64];       // (.x = c_b[i], .y = w2[i])
  __shared__ __align__(16) float scores[LONGN];
  __shared__ int   idsL[LONGN];
  __shared__ __align__(16) float redE[4*64];
  __shared__ __align__(16) float vecbuf[64];
  __shared__ float redV[4];
  __shared__ int   redI[4];
  __shared__ float selV[TOPKN];
  __shared__ int   selI[TOPKN];

  const int b = blockIdx.x;
  const int tid = threadIdx.x;
  const int wid = tid >> 6, lane = tid & 63;

  // ---- phase 0: load ids, target emb, build per-row A, c, w2 ----
  if (tid < 64) tv[tid] = item_emb[target_item_id[b]*64 + tid];
  for (int l = tid; l < LONGN; l += 256) idsL[l] = long_hist_ids[b*LONGN + l];
  __syncthreads();
  if (tid < 64) te[tid] = tproj_b[tid] + dotN<64>(tproj_w + tid*64, tv);
  __syncthreads();
  if (tid < 64) {
    float c = attn_b1[tid] + dotN<64>(attn_w1 + tid*192, te);
    cw[tid] = make_float2(c, attn_w2[tid]);
  }
  for (int idx = tid; idx < 4096; idx += 256) {
    int i = idx >> 6, j = idx & 63;
    A4[idx] = attn_w1[i*192 + 64 + j] + attn_w1[i*192 + 128 + j]*te[j];
  }
  __syncthreads();

  // ---- phase 1: scores for 1000 items (2 items per lane per round) ----
  const float b2s = attn_b2[0];
  for (int base = 0; base < LONGN; base += 512) {
    const int l0 = base + tid;
    const int l1 = l0 + 256;
    const bool has1 = (l1 < LONGN);
    const int id0 = idsL[l0];
    const int id1 = idsL[has1 ? l1 : l0];
    const float4* ep0 = (const float4*)(item_emb + id0*64);
    const float4* ep1 = (const float4*)(item_emb + id1*64);
    float4 e0[16], e1[16];
    #pragma unroll
    for (int k = 0; k < 16; ++k) { e0[k] = ep0[k]; e1[k] = ep1[k]; }
    float sc0 = b2s, sc1 = b2s;
    for (int i = 0; i < 64; ++i) {
      const float4* Ar = (const float4*)(A4 + i*64);
      float h00=0.f,h01=0.f,h02=0.f,h03=0.f;
      float h10=0.f,h11=0.f,h12=0.f,h13=0.f;
      #pragma unroll
      for (int k = 0; k < 16; k += 4) {
        float4 a0 = Ar[k], a1 = Ar[k+1], a2 = Ar[k+2], a3 = Ar[k+3];
        h00 += dot4(a0, e0[k]);   h01 += dot4(a1, e0[k+1]);
        h02 += dot4(a2, e0[k+2]); h03 += dot4(a3, e0[k+3]);
        h10 += dot4(a0, e1[k]);   h11 += dot4(a1, e1[k+1]);
        h12 += dot4(a2, e1[k+2]); h13 += dot4(a3, e1[k+3]);
      }
      float2 c2 = cw[i];
      float hh0 = ((h00+h01)+(h02+h03)) + c2.x;
      float hh1 = ((h10+h11)+(h12+h13)) + c2.x;
      sc0 += c2.y * fmaxf(hh0, 0.f);
      sc1 += c2.y * fmaxf(hh1, 0.f);
    }
    scores[l0] = sc0;
    if (has1) scores[l1] = sc1;
  }

  // ---- phase 1b: sum of long embeddings (for SDIM mean) ----
  float accE = 0.f;
  for (int l = wid; l < LONGN; l += 4)
    accE += item_emb[idsL[l]*64 + lane];
  redE[wid*64 + lane] = accE;
  __syncthreads();
  if (wid == 0)
    vecbuf[lane] = (redE[lane] + redE[64+lane] + redE[128+lane] + redE[192+lane]) * (1.f/1000.f);
  __syncthreads();

  // ---- phase 1c: hash bucket accumulation ----
  {
    const int hl = lane >> 4, dd = lane & 15;
    const float* hb = hash_emb + hl*1024*16 + dd;
    float accH = 0.f;
    for (int l = wid; l < LONGN; l += 4)
      accH += hb[(idsL[l] & 1023)*16];
    redE[wid*64 + lane] = accH;
  }
  __syncthreads();
  if (wid == 0)
    vecbuf[lane] += (redE[lane] + redE[64+lane] + redE[128+lane] + redE[192+lane]) * (1.f/1000.f);
  __syncthreads();
  // soft_repr = sdim_w @ (hash_repr + meanE) + sdim_b
  if (tid < 64)
    soft_out[b*64 + tid] = sdim_b[tid] + dotN<64>(sdim_w + tid*64, vecbuf);

  // ---- phase 2: softmax over 1000 scores -> attn probabilities ----
  float mx = -INFINITY;
  for (int l = tid; l < LONGN; l += 256) mx = fmaxf(mx, scores[l]);
  mx = wave_max(mx);
  if (lane == 0) redV[wid] = mx;
  __syncthreads();
  mx = fmaxf(fmaxf(redV[0], redV[1]), fmaxf(redV[2], redV[3]));
  __syncthreads();
  float sm = 0.f;
  for (int l = tid; l < LONGN; l += 256) {
    float a = expf(scores[l] - mx);
    scores[l] = a;
    sm += a;
  }
  sm = wave_sum(sm);
  if (lane == 0) redV[wid] = sm;
  __syncthreads();
  {
    const float inv = 1.f / (redV[0] + redV[1] + redV[2] + redV[3]);
    for (int l = tid; l < LONGN; l += 256) scores[l] *= inv;
  }
  __syncthreads();

  // ---- phase 3: iterative top-50 (max value, ties -> smallest index) ----
  for (int r = 0; r < TOPKN; ++r) {
    float bv = -1.f; int bi = 0x7fffffff;
    for (int l = tid; l < LONGN; l += 256) {
      float v = scores[l];
      if (v > bv || (v == bv && l < bi)) { bv = v; bi = l; }
    }
    #pragma unroll
    for (int off = 32; off > 0; off >>= 1) {
      float ov = __shfl_xor(bv, off);
      int   oi = __shfl_xor(bi, off);
      if (ov > bv || (ov == bv && oi < bi)) { bv = ov; bi = oi; }
    }
    if (lane == 0) { redV[wid] = bv; redI[wid] = bi; }
    __syncthreads();
    if (tid == 0) {
      float fv = redV[0]; int fi = redI[0];
      #pragma unroll
      for (int w = 1; w < 4; ++w)
        if (redV[w] > fv || (redV[w] == fv && redI[w] < fi)) { fv = redV[w]; fi = redI[w]; }
      selV[r] = fv; selI[r] = fi;
      scores[fi] = -1.f;   // remove winner (attn values are >= 0)
    }
    __syncthreads();
  }

  // ---- phase 4: softmax over the 50 selected attn values ----
  if (wid == 0) {
    float v = (lane < TOPKN) ? selV[lane] : -INFINITY;
    float m2 = wave_max(v);
    float e = (lane < TOPKN) ? expf(v - m2) : 0.f;
    float s2 = wave_sum(e);
    if (lane < TOPKN) selV[lane] = e / s2;
  }
  __syncthreads();

  // ---- phase 5: hard_repr = sum_r w_r * emb[ids[sel_r]] ----
  float accR = 0.f;
  for (int r = wid; r < TOPKN; r += 4)
    accR += selV[r] * item_emb[idsL[selI[r]]*64 + lane];
  redE[wid*64 + lane] = accR;
  __syncthreads();
  if (wid == 0)
    hard_out[b*64 + lane] = redE[lane] + redE[64+lane] + redE[128+lane] + redE[192+lane];
}

// ---------------------------------------------------------------------------
// Kernel 2: 2-layer BST transformer over short history. One block per row.
// v2: weight rows cached in VGPRs, reused across all 50 positions (cuts L2
// weight traffic 50x); q computed on-the-fly so only k,v staged in LDS
// (LDS 64KB -> 51.2KB). All xb/kvb/f1 LDS reads are wave-broadcast.
// ---------------------------------------------------------------------------
__global__ __launch_bounds__(256) void bst_kernel(
    const int* __restrict__ short_ids, const float* __restrict__ item_emb,
    const float* __restrict__ qkv_w, const float* __restrict__ qkv_b,
    const float* __restrict__ out_w, const float* __restrict__ out_b,
    const float* __restrict__ ln1_g, const float* __restrict__ ln1_b,
    const float* __restrict__ ff1_w, const float* __restrict__ ff1_b,
    const float* __restrict__ ff2_w, const float* __restrict__ ff2_b,
    const float* __restrict__ ln2_g, const float* __restrict__ ln2_b,
    float* __restrict__ bst_out)
{
  __shared__ __align__(16) float xb[SHORTN*64];    // 12.8 KB current x
  __shared__ __align__(16) float kvb[SHORTN*128];  // 25.6 KB k,v -> y -> f1
  __shared__ __align__(16) float ob[SHORTN*64];    // 12.8 KB attn-out -> y2

  const int b = blockIdx.x, tid = threadIdx.x;
  const int wid = tid >> 6, lane = tid & 63;

  for (int idx = tid; idx < SHORTN*64; idx += 256) {
    int s = idx >> 6, j = idx & 63;
    xb[idx] = item_emb[short_ids[b*SHORTN + s]*64 + j];
  }
  __syncthreads();

  for (int l = 0; l < 2; ++l) {
    const float* QW = qkv_w + l*12288;
    const float* QB = qkv_b + l*192;

    // ---- P1: k,v projection. thread = (col c of 128, s-half sg) ----
    {
      const int c  = tid & 127;
      const int sg = tid >> 7;
      const float* wr = QW + (64 + c)*64;
      float4 w[16];
      #pragma unroll
      for (int k = 0; k < 16; ++k) w[k] = ((const float4*)wr)[k];
      const float bias = QB[64 + c];
      for (int ii = 0; ii < 25; ++ii) {
        const int s = sg*25 + ii;
        kvb[s*128 + c] = bias + dotw16(w, (const float4*)(xb + s*64));
      }
    }
    __syncthreads();

    // ---- attention: thread = (h,s), q computed on the fly ----
    if (tid < 4*SHORTN) {
      const int h = tid / SHORTN, s = tid - h*SHORTN;
      float qq[16];
      #pragma unroll
      for (int j = 0; j < 16; ++j)
        qq[j] = QB[h*16+j] + dotN<64>(QW + (h*16+j)*64, xb + s*64);
      const float4 qA = make_float4(qq[0],qq[1],qq[2],qq[3]);
      const float4 qB2 = make_float4(qq[4],qq[5],qq[6],qq[7]);
      const float4 qC = make_float4(qq[8],qq[9],qq[10],qq[11]);
      const float4 qD = make_float4(qq[12],qq[13],qq[14],qq[15]);
      float mxa = -INFINITY;
      for (int t2 = 0; t2 < SHORTN; ++t2) {
        const float4* kp = (const float4*)(kvb + t2*128 + h*16);
        float d = dot4(qA,kp[0]) + dot4(qB2,kp[1]) + dot4(qC,kp[2]) + dot4(qD,kp[3]);
        mxa = fmaxf(mxa, d*0.25f);
      }
      float ss = 0.f;
      float4 oa0 = {0,0,0,0}, oa1 = {0,0,0,0}, oa2 = {0,0,0,0}, oa3 = {0,0,0,0};
      for (int t2 = 0; t2 < SHORTN; ++t2) {
        const float4* kp = (const float4*)(kvb + t2*128 + h*16);
        float d = dot4(qA,kp[0]) + dot4(qB2,kp[1]) + dot4(qC,kp[2]) + dot4(qD,kp[3]);
        float a = expf(d*0.25f - mxa);
        ss += a;
        const float4* vp = (const float4*)(kvb + t2*128 + 64 + h*16);
        float4 v0 = vp[0], v1 = vp[1], v2 = vp[2], v3 = vp[3];
        oa0.x += a*v0.x; oa0.y += a*v0.y; oa0.z += a*v0.z; oa0.w += a*v0.w;
        oa1.x += a*v1.x; oa1.y += a*v1.y; oa1.z += a*v1.z; oa1.w += a*v1.w;
        oa2.x += a*v2.x; oa2.y += a*v2.y; oa2.z += a*v2.z; oa2.w += a*v2.w;
        oa3.x += a*v3.x; oa3.y += a*v3.y; oa3.z += a*v3.z; oa3.w += a*v3.w;
      }
      const float inv = 1.f/ss;
      float4* op = (float4*)(ob + s*64 + h*16);
      oa0.x*=inv; oa0.y*=inv; oa0.z*=inv; oa0.w*=inv; op[0]=oa0;
      oa1.x*=inv; oa1.y*=inv; oa1.z*=inv; oa1.w*=inv; op[1]=oa1;
      oa2.x*=inv; oa2.y*=inv; oa2.z*=inv; oa2.w*=inv; op[2]=oa2;
      oa3.x*=inv; oa3.y*=inv; oa3.z*=inv; oa3.w*=inv; op[3]=oa3;
    }
    __syncthreads();

    // ---- out-proj + residual -> y in kvb[s*64+i] ----
    {
      const int i = tid & 63, sg = tid >> 6;
      const float* wr = out_w + l*4096 + i*64;
      float4 w[16];
      #pragma unroll
      for (int k = 0; k < 16; ++k) w[k] = ((const float4*)wr)[k];
      const float bias = out_b[l*64 + i];
      #pragma unroll
      for (int ii = 0; ii < 13; ++ii) {
        const int s = sg*13 + ii;
        if (s < SHORTN)
          kvb[s*64 + i] = xb[s*64 + i] + bias + dotw16(w, (const float4*)(ob + s*64));
      }
    }
    __syncthreads();

    // ---- LN1: kvb(y) -> xb ----
    {
      const float g = ln1_g[l*64 + lane], bb = ln1_b[l*64 + lane];
      for (int s = wid; s < SHORTN; s += 4) {
        float v = kvb[s*64 + lane];
        float mean = wave_sum(v) * (1.f/64.f);
        float dv = v - mean;
        float var = wave_sum(dv*dv) * (1.f/64.f);
        xb[s*64 + lane] = dv / sqrtf(var + 1e-5f) * g + bb;
      }
    }
    __syncthreads();

    // ---- ff1 + relu -> f1 in kvb[s*128+u] ----
    {
      const int u  = tid & 127;
      const int sg = tid >> 7;
      const float* wr = ff1_w + l*8192 + u*64;
      float4 w[16];
      #pragma unroll
      for (int k = 0; k < 16; ++k) w[k] = ((const float4*)wr)[k];
      const float bias = ff1_b[l*128 + u];
      for (int ii = 0; ii < 25; ++ii) {
        const int s = sg*25 + ii;
        kvb[s*128 + u] = fmaxf(bias + dotw16(w, (const float4*)(xb + s*64)), 0.f);
      }
    }
    __syncthreads();

    // ---- ff2 + residual -> y2 in ob (two-pass k-split, weights re-staged) ----
    {
      const int i = tid & 63, sg = tid >> 6;
      const float* wr = ff2_w + l*8192 + i*128;
      float4 w[16];
      #pragma unroll
      for (int k = 0; k < 16; ++k) w[k] = ((const float4*)wr)[k];
      float p[13];
      #pragma unroll
      for (int ii = 0; ii < 13; ++ii) {
        const int s = sg*13 + ii;
        if (s < SHORTN) p[ii] = dotw16(w, (const float4*)(kvb + s*128));
      }
      #pragma unroll
      for (int k = 0; k < 16; ++k) w[k] = ((const float4*)wr)[16 + k];
      const float bias = ff2_b[l*64 + i];
      #pragma unroll
      for (int ii = 0; ii < 13; ++ii) {
        const int s = sg*13 + ii;
        if (s < SHORTN)
          ob[s*64 + i] = xb[s*64 + i] + bias + p[ii]
                       + dotw16(w, (const float4*)(kvb + s*128 + 64));
      }
    }
    __syncthreads();

    // ---- LN2: ob(y2) -> xb ----
    {
      const float g = ln2_g[l*64 + lane], bb = ln2_b[l*64 + lane];
      for (int s = wid; s < SHORTN; s += 4) {
        float v = ob[s*64 + lane];
        float mean = wave_sum(v) * (1.f/64.f);
        float dv = v - mean;
        float var = wave_sum(dv*dv) * (1.f/64.f);
        xb[s*64 + lane] = dv / sqrtf(var + 1e-5f) * g + bb;
      }
    }
    __syncthreads();
  }

  // mean over sequence
  float acc = 0.f;
  for (int s = wid; s < SHORTN; s += 4) acc += xb[s*64 + lane];
  ob[wid*64 + lane] = acc;
  __syncthreads();
  if (wid == 0)
    bst_out[b*64 + lane] = (ob[lane] + ob[64+lane] + ob[128+lane] + ob[192+lane]) * (1.f/50.f);
}

// ---------------------------------------------------------------------------
// Kernel 3: fusion MLP. One block per row.
// ---------------------------------------------------------------------------
__global__ __launch_bounds__(256) void fusion_kernel(
    const float* __restrict__ user, const float* __restrict__ hard,
    const float* __restrict__ soft, const float* __restrict__ bst,
    const float* __restrict__ w1, const float* __restrict__ b1,
    const float* __restrict__ w2, const float* __restrict__ b2,
    const float* __restrict__ w3, const float* __restrict__ b3,
    float* __restrict__ out)
{
  __shared__ __align__(16) float comb[256];
  __shared__ __align__(16) float h1[256];
  __shared__ __align__(16) float h2[128];
  const int b = blockIdx.x, tid = threadIdx.x;
  if (tid < 64)       comb[tid] = user[b*64 + tid];
  else if (tid < 128) comb[tid] = hard[b*64 + tid - 64];
  else if (tid < 192) comb[tid] = soft[b*64 + tid - 128];
  else                comb[tid] = bst[b*64 + tid - 192];
  __syncthreads();
  h1[tid] = fmaxf(b1[tid] + dotN<256>(w1 + tid*256, comb), 0.f);
  __syncthreads();
  if (tid < 128) h2[tid] = fmaxf(b2[tid] + dotN<256>(w2 + tid*256, h1), 0.f);
  __syncthreads();
  if (tid < 64) {
    float p = w3[tid]*h2[tid] + w3[tid+64]*h2[tid+64];
    p = wave_sum(p);
    if (tid == 0) out[b] = p + b3[0];
  }
}

extern "C" void kernel_launch(void* const* d_in, const int* in_sizes, int n_in,
                              void* d_out, int out_size, void* d_ws, size_t ws_size,
                              hipStream_t stream) {
  const float* user_features  = (const float*)d_in[0];
  const int*   target_item_id = (const int*)  d_in[1];
  const int*   short_hist_ids = (const int*)  d_in[2];
  const int*   long_hist_ids  = (const int*)  d_in[3];
  const float* item_emb       = (const float*)d_in[4];
  const float* tproj_w  = (const float*)d_in[5];
  const float* tproj_b  = (const float*)d_in[6];
  const float* attn_w1  = (const float*)d_in[7];
  const float* attn_b1  = (const float*)d_in[8];
  const float* attn_w2  = (const float*)d_in[9];
  const float* attn_b2  = (const float*)d_in[10];
  const float* hash_emb = (const float*)d_in[11];
  const float* sdim_w   = (const float*)d_in[12];
  const float* sdim_b   = (const float*)d_in[13];
  const float* tf_qkv_w = (const float*)d_in[14];
  const float* tf_qkv_b = (const float*)d_in[15];
  const float* tf_out_w = (const float*)d_in[16];
  const float* tf_out_b = (const float*)d_in[17];
  const float* tf_ln1_g = (const float*)d_in[18];
  const float* tf_ln1_b = (const float*)d_in[19];
  const float* tf_ff1_w = (const float*)d_in[20];
  const float* tf_ff1_b = (const float*)d_in[21];
  const float* tf_ff2_w = (const float*)d_in[22];
  const float* tf_ff2_b = (const float*)d_in[23];
  const float* tf_ln2_g = (const float*)d_in[24];
  const float* tf_ln2_b = (const float*)d_in[25];
  const float* fus_w1   = (const float*)d_in[26];
  const float* fus_b1   = (const float*)d_in[27];
  const float* fus_w2   = (const float*)d_in[28];
  const float* fus_b2   = (const float*)d_in[29];
  const float* fus_w3   = (const float*)d_in[30];
  const float* fus_b3   = (const float*)d_in[31];

  float* hard = (float*)d_ws;
  float* soft = hard + NB*64;
  float* bst  = soft + NB*64;

  hardsoft_kernel<<<NB, 256, 0, stream>>>(target_item_id, long_hist_ids, item_emb,
      tproj_w, tproj_b, attn_w1, attn_b1, attn_w2, attn_b2,
      hash_emb, sdim_w, sdim_b, hard, soft);
  bst_kernel<<<NB, 256, 0, stream>>>(short_hist_ids, item_emb, tf_qkv_w, tf_qkv_b,
      tf_out_w, tf_out_b, tf_ln1_g, tf_ln1_b, tf_ff1_w, tf_ff1_b, tf_ff2_w, tf_ff2_b,
      tf_ln2_g, tf_ln2_b, bst);
  fusion_kernel<<<NB, 256, 0, stream>>>(user_features, hard, soft, bst,
      fus_w1, fus_b1, fus_w2, fus_b2, fus_w3, fus_b3, (float*)d_out);
}